// Round 22
// baseline (169.645 us; speedup 1.0000x reference)
//
#include <hip/hip_runtime.h>
#include <hip/hip_bf16.h>
#include <stdint.h>

typedef __attribute__((ext_vector_type(8))) short short8;
typedef __attribute__((ext_vector_type(4))) float f32x4;

__device__ __forceinline__ unsigned short f2bf(float f) {
    union { float f; uint32_t u; } v; v.f = f;
    return (unsigned short)((v.u + 0x7FFFu + ((v.u >> 16) & 1u)) >> 16);
}

// Build W in MFMA-FRAGMENT order with the LINE-COALESCED k-map (R13, unchanged):
//   lane (l15,lhi), elem e holds k = c*32 + (e<4 ? lhi*4+e : 16+lhi*4+(e-4))
//   Wfrag[((ct*6 + c)*64 + lane)*8 + e] = bf16( W[ct*16 + (lane&15)][k] )
// where W[j][k] = kernel[cayley[inv[k>>4], j>>4]][j&15][k&15].
__global__ void build_w_kernel(const float* __restrict__ kern,
                               const int* __restrict__ cayley,
                               const int* __restrict__ inv,
                               unsigned short* __restrict__ Wfrag) {
    int i = blockIdx.x * blockDim.x + threadIdx.x;   // i = ((ct*6+c)*64 + lane)*8 + e
    if (i >= 192 * 192) return;
    int e    = i & 7;
    int lane = (i >> 3) & 63;
    int fc   = i >> 9;            // ct*6 + c
    int ct   = fc / 6, c = fc - ct * 6;
    int j = ct * 16 + (lane & 15);
    int lhi = lane >> 4;
    int k = c * 32 + ((e < 4) ? (lhi * 4 + e) : (16 + lhi * 4 + (e - 4)));
    int h = j >> 4, oc = j & 15;
    int g = k >> 4, ic = k & 15;
    int cidx = cayley[inv[g] * 12 + h];
    Wfrag[i] = f2bf(kern[cidx * 256 + oc * 16 + ic]);
}

// out[n][j] = sum_k x[n][k] * W[j][k] + bias[j]
// R21 = R20 (copy-shaped global instrs, 168.3us best) + DOUBLE-BUFFERED bounces:
// 2 syncs/strip instead of 3, and stores(N) overlap deposit+prefetch(N+1) with
// no barrier between. Hazard audit: xb[cur] reused at N+2 — deposit(N+2) is
// after sync2(N+1) > all frag-reads(N); ob[cur] reused at N+2 — MFMA-writes
// (N+2) after sync1(N+2) > store-reads(N) which precede sync1(N+1). Safe.
// LDS 2x(12544+12544) = 50176 B -> 3 blocks/CU. (256,1) => 256 cap (ledger;
// R19/R20 clean). W in regs 3 cts/wave; R13 k-map; plain stores.
__global__ __launch_bounds__(256, 1) void gemm_kernel(
    const float* __restrict__ x,
    const unsigned short* __restrict__ Wfrag,
    const float* __restrict__ bias,
    float* __restrict__ out, int nstrips, int spb) {
  __shared__ unsigned char xb[2][16 * 784];   // rows padded 768->784
  __shared__ unsigned char ob[2][16 * 784];
  const int tid  = threadIdx.x;
  const int lane = tid & 63;
  const int wid  = tid >> 6;          // 0..3 -> owns cts [3*wid, 3*wid+3)
  const int l15  = lane & 15;
  const int lhi  = lane >> 4;

  // This wave's 18 W fragments in registers (one-time, L2-resident).
  short8 wf[3][6];
  #pragma unroll
  for (int t = 0; t < 3; ++t)
    #pragma unroll
    for (int c = 0; c < 6; ++c)
      wf[t][c] = *(const short8*)(Wfrag + (((wid * 3 + t) * 6 + c) * 64 + lane) * 8);

  // bias for this lane's 4 output features (oc = lhi*4+r, ct-independent)
  const f32x4 bias4 = *(const f32x4*)(bias + lhi * 4);

  // Hoisted strip-invariant addressing.
  int goff[3], coff[3];   // global byte offset within strip; LDS byte offset
  #pragma unroll
  for (int t = 0; t < 3; ++t) {
    int idx = ((wid * 3 + t) << 6) + lane;          // (instr)*64 + lane
    int row = idx / 48;                             // 48 chunks of 16B per 768B row
    int cb  = idx - row * 48;
    goff[t] = idx << 4;
    coff[t] = row * 784 + (cb << 4);
  }
  const int fbase = l15 * 784 + lhi * 16;
  int obw[3];
  #pragma unroll
  for (int t = 0; t < 3; ++t) obw[t] = l15 * 784 + (wid * 3 + t) * 64 + lhi * 16;

  int strip = blockIdx.x * spb;
  const int send = min(strip + spb, nstrips);
  if (strip >= send) return;

  // Prologue: issue strip 0's contiguous loads.
  f32x4 pre[3];
  {
    const unsigned char* xs = (const unsigned char*)x + (size_t)strip * 12288;
    #pragma unroll
    for (int t = 0; t < 3; ++t) pre[t] = *(const f32x4*)(xs + goff[t]);
  }

  int cur = 0;
  while (strip < send) {
    unsigned char* xcur = xb[cur];
    unsigned char* ocur = ob[cur];

    // Deposit this strip's x into the current bounce.
    #pragma unroll
    for (int t = 0; t < 3; ++t) *(f32x4*)(xcur + coff[t]) = pre[t];

    // Prefetch next strip's contiguous loads (ride through compute+stores).
    const int nxt = strip + 1;
    if (nxt < send) {
      const unsigned char* xs = (const unsigned char*)x + (size_t)nxt * 12288;
      #pragma unroll
      for (int t = 0; t < 3; ++t) pre[t] = *(const f32x4*)(xs + goff[t]);
    }
    __syncthreads();                       // sync1: xb[cur] ready

    // Fragment reads + cvt (R13 k-map).
    short8 abf[6];
    #pragma unroll
    for (int c = 0; c < 6; ++c) {
      f32x4 lo = *(const f32x4*)(xcur + fbase + c * 128);
      f32x4 hi = *(const f32x4*)(xcur + fbase + c * 128 + 64);
      short8 v;
      #pragma unroll
      for (int e = 0; e < 4; ++e) {
        v[e]     = (short)f2bf(lo[e]);
        v[e + 4] = (short)f2bf(hi[e]);
      }
      abf[c] = v;
    }

    // MFMA: this wave's 3 cts; results (+bias) into the out-bounce.
    #pragma unroll
    for (int t = 0; t < 3; ++t) {
      f32x4 acc = {0.f, 0.f, 0.f, 0.f};
      #pragma unroll
      for (int c = 0; c < 6; ++c)
        acc = __builtin_amdgcn_mfma_f32_16x16x32_bf16(wf[t][c], abf[c], acc, 0, 0, 0);
      f32x4 res = {acc[0] + bias4[0], acc[1] + bias4[1],
                   acc[2] + bias4[2], acc[3] + bias4[3]};
      *(f32x4*)(ocur + obw[t]) = res;
    }
    __syncthreads();                       // sync2: ob[cur] ready

    // Contiguous copy-shaped stores; overlap next iteration's deposit/prefetch.
    {
      unsigned char* os = (unsigned char*)out + (size_t)strip * 12288;
      #pragma unroll
      for (int t = 0; t < 3; ++t) {
        f32x4 v = *(const f32x4*)(ocur + coff[t]);
        *(f32x4*)(os + goff[t]) = v;
      }
    }
    strip = nxt;
    cur ^= 1;
  }
}

extern "C" void kernel_launch(void* const* d_in, const int* in_sizes, int n_in,
                              void* d_out, int out_size, void* d_ws, size_t ws_size,
                              hipStream_t stream) {
    const float* x      = (const float*)d_in[0];
    const float* kern   = (const float*)d_in[1];
    const float* bias   = (const float*)d_in[2];
    const int*   cayley = (const int*)d_in[3];
    const int*   inv    = (const int*)d_in[4];
    float* out = (float*)d_out;
    unsigned short* Wfrag = (unsigned short*)d_ws;   // 73728 bytes

    const int nrows = in_sizes[0] / 192;
    const int nstrips = nrows / 16;                  // 32768

    build_w_kernel<<<(192 * 192 + 255) / 256, 256, 0, stream>>>(kern, cayley, inv, Wfrag);

    const int nblocks = 2048;                        // 16 strips per block
    const int spb     = (nstrips + nblocks - 1) / nblocks;
    gemm_kernel<<<nblocks, 256, 0, stream>>>(x, Wfrag, bias, out, nstrips, spb);
}

// Round 23
// 168.573 us; speedup vs baseline: 1.0064x; 1.0064x over previous
//
#include <hip/hip_runtime.h>
#include <hip/hip_bf16.h>
#include <stdint.h>

typedef __attribute__((ext_vector_type(8))) short short8;
typedef __attribute__((ext_vector_type(4))) float f32x4;

__device__ __forceinline__ unsigned short f2bf(float f) {
    union { float f; uint32_t u; } v; v.f = f;
    return (unsigned short)((v.u + 0x7FFFu + ((v.u >> 16) & 1u)) >> 16);
}

// Build W in MFMA-FRAGMENT order with the LINE-COALESCED k-map (R13, unchanged):
//   lane (l15,lhi), elem e holds k = c*32 + (e<4 ? lhi*4+e : 16+lhi*4+(e-4))
//   Wfrag[((ct*6 + c)*64 + lane)*8 + e] = bf16( W[ct*16 + (lane&15)][k] )
// where W[j][k] = kernel[cayley[inv[k>>4], j>>4]][j&15][k&15].
__global__ void build_w_kernel(const float* __restrict__ kern,
                               const int* __restrict__ cayley,
                               const int* __restrict__ inv,
                               unsigned short* __restrict__ Wfrag) {
    int i = blockIdx.x * blockDim.x + threadIdx.x;   // i = ((ct*6+c)*64 + lane)*8 + e
    if (i >= 192 * 192) return;
    int e    = i & 7;
    int lane = (i >> 3) & 63;
    int fc   = i >> 9;            // ct*6 + c
    int ct   = fc / 6, c = fc - ct * 6;
    int j = ct * 16 + (lane & 15);
    int lhi = lane >> 4;
    int k = c * 32 + ((e < 4) ? (lhi * 4 + e) : (16 + lhi * 4 + (e - 4)));
    int h = j >> 4, oc = j & 15;
    int g = k >> 4, ic = k & 15;
    int cidx = cayley[inv[g] * 12 + h];
    Wfrag[i] = f2bf(kern[cidx * 256 + oc * 16 + ic]);
}

// out[n][j] = sum_k x[n][k] * W[j][k] + bias[j]
// R22 = R20 (copy-shaped globals, 168.3us best; R21 dbuf was neutral) +
// DEPTH-2 PREFETCH via 2x-unrolled strip loop with two NAMED reg sets
// (preA/preB — no runtime-indexed arrays, which go to scratch). Little's law:
// ~2 resident blocks/CU x 3KB (depth-1) = 6KB in flight < the 10-25KB needed
// to sustain 24.6 GB/s/CU; depth-2 doubles it. vmcnt audit: each deposit waits
// its own set's loads, which are OLDER than the preceding phase's stores ->
// in-order retirement never makes a deposit wait store acks.
// (256,1) => 256 cap (ledger; R19/R20 clean). W in regs 3 cts/wave; R13 k-map;
// plain stores; single-buffer bounces, 3 syncs/strip (R20 pattern).
__global__ __launch_bounds__(256, 1) void gemm_kernel(
    const float* __restrict__ x,
    const unsigned short* __restrict__ Wfrag,
    const float* __restrict__ bias,
    float* __restrict__ out, int nstrips, int spb) {
  __shared__ unsigned char xb[16 * 784];   // rows padded 768->784
  __shared__ unsigned char ob[16 * 784];
  const int tid  = threadIdx.x;
  const int lane = tid & 63;
  const int wid  = tid >> 6;          // 0..3 -> owns cts [3*wid, 3*wid+3)
  const int l15  = lane & 15;
  const int lhi  = lane >> 4;

  // This wave's 18 W fragments in registers (one-time, L2-resident).
  short8 wf[3][6];
  #pragma unroll
  for (int t = 0; t < 3; ++t)
    #pragma unroll
    for (int c = 0; c < 6; ++c)
      wf[t][c] = *(const short8*)(Wfrag + (((wid * 3 + t) * 6 + c) * 64 + lane) * 8);

  // bias for this lane's 4 output features (oc = lhi*4+r, ct-independent)
  const f32x4 bias4 = *(const f32x4*)(bias + lhi * 4);

  // Hoisted strip-invariant addressing.
  int goff[3], coff[3];
  #pragma unroll
  for (int t = 0; t < 3; ++t) {
    int idx = ((wid * 3 + t) << 6) + lane;          // (instr)*64 + lane
    int row = idx / 48;                             // 48 x 16B chunks per 768B row
    int cb  = idx - row * 48;
    goff[t] = idx << 4;
    coff[t] = row * 784 + (cb << 4);
  }
  const int fbase = l15 * 784 + lhi * 16;
  int obw[3];
  #pragma unroll
  for (int t = 0; t < 3; ++t) obw[t] = l15 * 784 + (wid * 3 + t) * 64 + lhi * 16;

  const int s0 = blockIdx.x * spb;
  const int send = min(s0 + spb, nstrips);
  if (s0 >= send) return;
  // spb is even (16); process strips in pairs.

  f32x4 preA[3], preB[3];
  // Prologue: strip s0 -> preA, s0+1 -> preB.
  {
    const unsigned char* xs = (const unsigned char*)x + (size_t)s0 * 12288;
    #pragma unroll
    for (int t = 0; t < 3; ++t) preA[t] = *(const f32x4*)(xs + goff[t]);
  }
  if (s0 + 1 < send) {
    const unsigned char* xs = (const unsigned char*)x + (size_t)(s0 + 1) * 12288;
    #pragma unroll
    for (int t = 0; t < 3; ++t) preB[t] = *(const f32x4*)(xs + goff[t]);
  }

#define PHASE(PRE, STRIP, PFSTRIP)                                            \
  {                                                                           \
    const int st = (STRIP);                                                   \
    if (st < send) {                                                          \
      /* Deposit: waits only PRE's 3 loads (older than any later stores). */  \
      _Pragma("unroll")                                                       \
      for (int t = 0; t < 3; ++t) *(f32x4*)(xb + coff[t]) = PRE[t];           \
      __syncthreads();                                                        \
      short8 abf[6];                                                          \
      _Pragma("unroll")                                                       \
      for (int c = 0; c < 6; ++c) {                                           \
        f32x4 lo = *(const f32x4*)(xb + fbase + c * 128);                     \
        f32x4 hi = *(const f32x4*)(xb + fbase + c * 128 + 64);                \
        short8 v;                                                             \
        _Pragma("unroll")                                                     \
        for (int e = 0; e < 4; ++e) {                                         \
          v[e]     = (short)f2bf(lo[e]);                                      \
          v[e + 4] = (short)f2bf(hi[e]);                                      \
        }                                                                     \
        abf[c] = v;                                                           \
      }                                                                       \
      /* Reissue PRE 2 strips ahead: read queue never drains. */              \
      const int pf = (PFSTRIP);                                               \
      if (pf < send) {                                                        \
        const unsigned char* xs = (const unsigned char*)x + (size_t)pf * 12288;\
        _Pragma("unroll")                                                     \
        for (int t = 0; t < 3; ++t) PRE[t] = *(const f32x4*)(xs + goff[t]);   \
      }                                                                       \
      _Pragma("unroll")                                                       \
      for (int t = 0; t < 3; ++t) {                                           \
        f32x4 acc = {0.f, 0.f, 0.f, 0.f};                                     \
        _Pragma("unroll")                                                     \
        for (int c = 0; c < 6; ++c)                                           \
          acc = __builtin_amdgcn_mfma_f32_16x16x32_bf16(wf[t][c], abf[c], acc, 0, 0, 0); \
        f32x4 res = {acc[0] + bias4[0], acc[1] + bias4[1],                    \
                     acc[2] + bias4[2], acc[3] + bias4[3]};                   \
        *(f32x4*)(ob + obw[t]) = res;                                         \
      }                                                                       \
      __syncthreads();                                                        \
      {                                                                       \
        unsigned char* os = (unsigned char*)out + (size_t)st * 12288;         \
        _Pragma("unroll")                                                     \
        for (int t = 0; t < 3; ++t) {                                         \
          f32x4 v = *(const f32x4*)(ob + coff[t]);                            \
          *(f32x4*)(os + goff[t]) = v;                                        \
        }                                                                     \
      }                                                                       \
      __syncthreads();                                                        \
    }                                                                         \
  }

  for (int s = s0; s < send; s += 2) {
    PHASE(preA, s,     s + 2);
    PHASE(preB, s + 1, s + 3);
  }
#undef PHASE
}

extern "C" void kernel_launch(void* const* d_in, const int* in_sizes, int n_in,
                              void* d_out, int out_size, void* d_ws, size_t ws_size,
                              hipStream_t stream) {
    const float* x      = (const float*)d_in[0];
    const float* kern   = (const float*)d_in[1];
    const float* bias   = (const float*)d_in[2];
    const int*   cayley = (const int*)d_in[3];
    const int*   inv    = (const int*)d_in[4];
    float* out = (float*)d_out;
    unsigned short* Wfrag = (unsigned short*)d_ws;   // 73728 bytes

    const int nrows = in_sizes[0] / 192;
    const int nstrips = nrows / 16;                  // 32768

    build_w_kernel<<<(192 * 192 + 255) / 256, 256, 0, stream>>>(kern, cayley, inv, Wfrag);

    const int nblocks = 2048;                        // 16 strips per block (even)
    const int spb     = (nstrips + nblocks - 1) / nblocks;
    gemm_kernel<<<nblocks, 256, 0, stream>>>(x, Wfrag, bias, out, nstrips, spb);
}